// Round 13
// baseline (53.990 us; speedup 1.0000x reference)
//
#include <hip/hip_runtime.h>

typedef __attribute__((ext_vector_type(8))) short bf16x8;
typedef __attribute__((ext_vector_type(4))) float f32x4;

namespace {
constexpr int NB=8, N1=4096, N2=1024, F1=128, F2=256, H2=256;
constexpr int TM=32;
constexpr float SLOPE=0.2f, EPSD=1e-10f;
constexpr size_t WS_W1=0;                     // 192 KB (12 steps * 16 frags * 1KB)
constexpr size_t WS_W2=196608;                // 128 KB
constexpr int XT_STRIDE=784;   // 48 slots*16B + 16B pad
constexpr int H_STRIDE=528;    // 512B row + 16B pad
}

__device__ __forceinline__ unsigned short f2bf(float f){
  union{float f; unsigned u;} v; v.f=f;
  unsigned r = v.u + 0x7FFFu + ((v.u>>16)&1u);   // RNE
  return (unsigned short)(r>>16);
}
// packed RNE f32x2 -> bf16x2 (bit-identical to f2bf, 1 instr)
__device__ __forceinline__ unsigned cvt_pk_bf16(float lo, float hi){
  unsigned r;
  asm("v_cvt_pk_bf16_f32 %0, %1, %2" : "=v"(r) : "v"(lo), "v"(hi));
  return r;
}
__device__ __forceinline__ float lrelu(float x){ return x>=0.f? x : SLOPE*x; }

// ===== W1/W2 -> bf16 frag-linear: frag = s*16 + nq*4 + nt; lane ln holds 8
// k-bf16 for n = nq*64+nt*16+(ln&15), k0 = s*32+(ln>>4)*8 =====
__global__ __launch_bounds__(256)
void transform_w(const float* __restrict__ W1, const float* __restrict__ W2,
                 char* __restrict__ ws)
{
  int id = blockIdx.x*256 + threadIdx.x;
  const float* src; size_t dst;
  if (id < 12288) {                             // W1: 192 frags
    int frag = id >> 6, ln = id & 63;
    int n = (((frag>>2)&3)*64) + ((frag&3)*16) + (ln & 15);
    int k0 = (frag>>4)*32 + (ln>>4)*8;
    src = W1 + (size_t)k0*256 + n;
    dst = WS_W1 + (size_t)frag*1024 + ln*16;
  } else if (id < 20480) {                      // W2: 128 frags
    int fid = id - 12288, frag = fid >> 6, ln = fid & 63;
    int n = (((frag>>2)&3)*64) + ((frag&3)*16) + (ln & 15);
    int k0 = (frag>>4)*32 + (ln>>4)*8;
    src = W2 + (size_t)k0*256 + n;
    dst = WS_W2 + (size_t)frag*1024 + ln*16;
  } else return;
  unsigned u[4];
  #pragma unroll
  for (int p=0;p<4;++p)
    u[p] = (unsigned)f2bf(src[(2*p)*256]) | ((unsigned)f2bf(src[(2*p+1)*256])<<16);
  *(uint4*)(ws + dst) = make_uint4(u[0],u[1],u[2],u[3]);
}

// TM=32, 512 threads (8 waves = 2m x 4n), grid 1024 -> 4 blocks/CU = 32 waves/CU.
// Same W-traffic & fixed costs as R10 (1024 blocks), double the waves.
__global__ __launch_bounds__(512, 4)
void fp_mfma(const float* __restrict__ xyz1, const float* __restrict__ xyz2,
             const float* __restrict__ p1,   const float* __restrict__ p2,
             const char* __restrict__ ws,
             const float* __restrict__ b1,   const float* __restrict__ b2,
             float* __restrict__ out)
{
  __shared__ __align__(16) char smem[32768];   // xq16K+cand16K -> Xt25K -> h17K
  __shared__ float s_w[TM][4];
  __shared__ int   s_idx[TM][4];

  const int t = threadIdx.x;
  const int b = blockIdx.x & 7;                // batch == XCD
  const int row0 = (blockIdx.x >> 3) * TM;
  const int lane = t & 63, wv = t >> 6;
  const int lrow = lane & 15, lg = lane >> 4;
  const int mh = wv >> 2, nq = wv & 3;         // wave = (m-half, n-quad)

  // ===== Phase A: stage xyz2 -> LDS; 16 slices x 64 j; 2-stage merge =====
  {
    float4* xq = (float4*)smem;                // [0, 16384)
    char* cand = smem + 16384;                 // [16384, 32768): 512*32B
    const float* xz = xyz2 + (size_t)b*N2*3;
    for (int j = t; j < N2; j += 512) {
      float x = xz[3*j], y = xz[3*j+1], z = xz[3*j+2];
      xq[j] = make_float4(x, y, z, x*x + y*y + z*z);
    }
    __syncthreads();
    {
      const int row = t & 31, slice = t >> 5;  // half-wave-uniform j -> broadcast
      const float* x1 = xyz1 + ((size_t)b*N1 + row0 + row)*3;
      const float px=x1[0], py=x1[1], pz=x1[2];
      const float sq1 = px*px + py*py + pz*pz;
      float d0=3.4e38f, d1=3.4e38f, d2=3.4e38f;
      int i0=0, i1=0, i2=0;
      const int j0 = slice*64;
      #pragma unroll 8
      for (int j = j0; j < j0+64; ++j) {
        float4 q = xq[j];
        float dot = px*q.x + py*q.y + pz*q.z;
        float d = fmaf(-2.f, dot, sq1 + q.w);
        bool c0 = d < d0, c1 = d < d1, c2 = d < d2;
        i2 = c1 ? i1 : (c2 ? j : i2);
        i1 = c0 ? i0 : (c1 ? j : i1);
        i0 = c0 ? j  : i0;
        d2 = __builtin_amdgcn_fmed3f(d, d1, d2);
        d1 = __builtin_amdgcn_fmed3f(d, d0, d1);
        d0 = fminf(d, d0);
      }
      float* cd = (float*)(cand + (slice*32 + row)*32);
      cd[0]=d0; cd[1]=d1; cd[2]=d2;
      ((int*)cd)[4]=i0; ((int*)cd)[5]=i1; ((int*)cd)[6]=i2;
    }
    __syncthreads();
    // stage 1: 128 threads, each merges 4 ascending slices -> cand2 (xq region)
    if (t < 128) {
      const int row = t & 31, grp = t >> 5;
      const char* cand_ = smem + 16384;
      float d0=3.4e38f,d1=3.4e38f,d2=3.4e38f; int i0=0,i1=0,i2=0;
      for (int c4=0;c4<4;++c4){
        const float* cd = (const float*)(cand_ + ((grp*4 + c4)*32 + row)*32);
        for (int c=0;c<3;++c){
          float d = cd[c]; int ii = ((const int*)cd)[4+c];
          if (d < d2) {
            if (d < d1) { d2=d1; i2=i1;
              if (d < d0) { d1=d0; i1=i0; d0=d; i0=ii; } else { d1=d; i1=ii; }
            } else { d2=d; i2=ii; }
          }
        }
      }
      float* cd2 = (float*)(smem + (grp*32 + row)*32);
      cd2[0]=d0; cd2[1]=d1; cd2[2]=d2;
      ((int*)cd2)[4]=i0; ((int*)cd2)[5]=i1; ((int*)cd2)[6]=i2;
    }
    __syncthreads();
    // stage 2: 32 threads merge 4 groups (ascending) -> weights
    if (t < TM) {
      float d0=3.4e38f,d1=3.4e38f,d2=3.4e38f; int i0=0,i1=0,i2=0;
      for (int p=0;p<4;++p){
        const float* cd = (const float*)(smem + (p*32 + t)*32);
        for (int c=0;c<3;++c){
          float d = cd[c]; int ii = ((const int*)cd)[4+c];
          if (d < d2) {
            if (d < d1) { d2=d1; i2=i1;
              if (d < d0) { d1=d0; i1=i0; d0=d; i0=ii; } else { d1=d; i1=ii; }
            } else { d2=d; i2=ii; }
          }
        }
      }
      d0=fmaxf(d0,EPSD); d1=fmaxf(d1,EPSD); d2=fmaxf(d2,EPSD);
      float w0=1.f/d0, w1=1.f/d1, w2=1.f/d2, inv=1.f/(w0+w1+w2);
      s_w[t][0]=w0*inv; s_w[t][1]=w1*inv; s_w[t][2]=w2*inv;
      s_idx[t][0]=i0; s_idx[t][1]=i1; s_idx[t][2]=i2;
    }
    __syncthreads();
  }

  // ===== Phase B =====
  const int rr = t >> 4, qq = t & 15;          // X build: 16 thr/row, 3 slots each
  const float w0_=s_w[rr][0], w1_=s_w[rr][1], w2_=s_w[rr][2];
  const int g0=s_idx[rr][0], g1=s_idx[rr][1], g2=s_idx[rr][2];
  const char* wsW1 = ws + WS_W1;
  const char* wsW2 = ws + WS_W2;
  const float* p2b = p2 + (size_t)b*N2*F2;
  const float* p1r = p1 + ((size_t)b*N1 + row0 + rr)*F1;

  auto issueS = [&](int s, float4* g){         // slot s in 0..47, 8 k each
    if (s < 32) {
      const int k0 = s*8;
      const float4* q0 = (const float4*)(p2b + (size_t)g0*F2 + k0);
      const float4* q1 = (const float4*)(p2b + (size_t)g1*F2 + k0);
      const float4* q2 = (const float4*)(p2b + (size_t)g2*F2 + k0);
      g[0]=q0[0]; g[1]=q0[1]; g[2]=q1[0]; g[3]=q1[1]; g[4]=q2[0]; g[5]=q2[1];
    } else {
      const float4* q = (const float4*)(p1r + (s*8 - F2));
      g[0]=q[0]; g[1]=q[1];
    }
  };
  auto writeS = [&](int s, const float4* g){
    float v[8];
    if (s < 32) {
      #pragma unroll
      for (int p=0;p<2;++p){
        v[4*p+0] = fmaf(w2_, g[4+p].x, fmaf(w1_, g[2+p].x, w0_*g[p].x));
        v[4*p+1] = fmaf(w2_, g[4+p].y, fmaf(w1_, g[2+p].y, w0_*g[p].y));
        v[4*p+2] = fmaf(w2_, g[4+p].z, fmaf(w1_, g[2+p].z, w0_*g[p].z));
        v[4*p+3] = fmaf(w2_, g[4+p].w, fmaf(w1_, g[2+p].w, w0_*g[p].w));
      }
    } else {
      #pragma unroll
      for (int p=0;p<2;++p){
        v[4*p+0]=g[p].x; v[4*p+1]=g[p].y; v[4*p+2]=g[p].z; v[4*p+3]=g[p].w;
      }
    }
    unsigned u[4];
    #pragma unroll
    for (int p=0;p<4;++p) u[p] = cvt_pk_bf16(v[2*p], v[2*p+1]);
    *(uint4*)(smem + rr*XT_STRIDE + s*16) = make_uint4(u[0],u[1],u[2],u[3]);
  };
  auto loadW = [&](const char* base, int s, bf16x8* dst){
    #pragma unroll
    for (int nt=0;nt<4;++nt)
      dst[nt] = *(const bf16x8*)(base + ((s*16 + nq*4 + nt)<<10) + lane*16);
  };
  auto gemmStep = [&](int s, const bf16x8* bw, f32x4 (&ac)[4],
                      const char* Ab, int stride){
    bf16x8 af = *(const bf16x8*)(Ab + (mh*16 + lrow)*stride + (s*4+lg)*16);
    #pragma unroll
    for (int nt=0;nt<4;++nt)
      ac[nt] = __builtin_amdgcn_mfma_f32_16x16x32_bf16(af, bw[nt], ac[nt], 0,0,0);
  };

  f32x4 acc[4];
  #pragma unroll
  for (int nt=0;nt<4;++nt) acc[nt] = (f32x4){0.f,0.f,0.f,0.f};

  // ---- W steps 0..2 prefetch FIRST (L2 latency hides under X build) ----
  bf16x8 bwA[4], bwB[4], bwC[4];
  loadW(wsW1, 0, bwA);
  loadW(wsW1, 1, bwB);
  loadW(wsW1, 2, bwC);

  // ---- build full X tile (32 x 384), depth-2 gather pipeline ----
  float4 ga[6], gb[6];
  issueS(qq,      ga); issueS(qq+16, gb);
  writeS(qq,      ga); issueS(qq+32, ga);
  writeS(qq+16,   gb); writeS(qq+32, ga);
  __syncthreads();

  // ---- GEMM1: 12 K32 steps, no internal barriers, W prefetch distance 3 ----
  #pragma unroll
  for (int u=0; u<4; ++u) {
    gemmStep(3*u,   bwA, acc, smem, XT_STRIDE);
    if (u<3) loadW(wsW1, 3*u+3, bwA); else loadW(wsW2, 0, bwA);
    gemmStep(3*u+1, bwB, acc, smem, XT_STRIDE);
    if (u<3) loadW(wsW1, 3*u+4, bwB); else loadW(wsW2, 1, bwB);
    gemmStep(3*u+2, bwC, acc, smem, XT_STRIDE);
    if (u<3) loadW(wsW1, 3*u+5, bwC); else loadW(wsW2, 2, bwC);
  }
  __syncthreads();                             // Xt dead

  // ---- h = lrelu(acc + b1) -> LDS [32][264 shorts], cvt_pk pairs ----
  {
    float bb[4];
    #pragma unroll
    for (int nt=0;nt<4;++nt) bb[nt] = b1[nq*64 + nt*16 + lrow];
    #pragma unroll
    for (int rg=0;rg<4;++rg) {
      const int row = mh*16 + lg*4 + rg;
      char* hb = smem + row*H_STRIDE + (nq*64 + lrow)*2;
      float v0 = lrelu(acc[0][rg] + bb[0]);
      float v1 = lrelu(acc[1][rg] + bb[1]);
      float v2 = lrelu(acc[2][rg] + bb[2]);
      float v3 = lrelu(acc[3][rg] + bb[3]);
      unsigned pA = cvt_pk_bf16(v0, v1), pB = cvt_pk_bf16(v2, v3);
      *(short*)(hb)      = (short)pA;
      *(short*)(hb + 32) = (short)(pA >> 16);
      *(short*)(hb + 64) = (short)pB;
      *(short*)(hb + 96) = (short)(pB >> 16);
    }
  }
  __syncthreads();

  // ---- GEMM2: h(32x256) @ W2, 8 K32 steps, dist-3 rotation ----
  f32x4 acc2[4];
  #pragma unroll
  for (int nt=0;nt<4;++nt) acc2[nt] = (f32x4){0.f,0.f,0.f,0.f};
  gemmStep(0, bwA, acc2, smem, H_STRIDE); loadW(wsW2, 3, bwA);
  gemmStep(1, bwB, acc2, smem, H_STRIDE); loadW(wsW2, 4, bwB);
  gemmStep(2, bwC, acc2, smem, H_STRIDE); loadW(wsW2, 5, bwC);
  gemmStep(3, bwA, acc2, smem, H_STRIDE); loadW(wsW2, 6, bwA);
  gemmStep(4, bwB, acc2, smem, H_STRIDE); loadW(wsW2, 7, bwB);
  gemmStep(5, bwC, acc2, smem, H_STRIDE);
  gemmStep(6, bwA, acc2, smem, H_STRIDE);
  gemmStep(7, bwB, acc2, smem, H_STRIDE);

  // ---- epilogue ----
  {
    float bb[4];
    #pragma unroll
    for (int nt=0;nt<4;++nt) bb[nt] = b2[nq*64 + nt*16 + lrow];
    float* ob = out + ((size_t)b*N1 + row0) * H2;
    #pragma unroll
    for (int rg=0;rg<4;++rg) {
      const int row = mh*16 + lg*4 + rg;
      #pragma unroll
      for (int nt=0;nt<4;++nt) {
        const int col = nq*64 + nt*16 + lrow;
        ob[(size_t)row*H2 + col] = lrelu(acc2[nt][rg] + bb[nt]);
      }
    }
  }
}

extern "C" void kernel_launch(void* const* d_in, const int* in_sizes, int n_in,
                              void* d_out, int out_size, void* d_ws, size_t ws_size,
                              hipStream_t stream) {
  const float* xyz1    = (const float*)d_in[0];
  const float* xyz2    = (const float*)d_in[1];
  const float* points1 = (const float*)d_in[2];
  const float* points2 = (const float*)d_in[3];
  const float* W1      = (const float*)d_in[4];
  const float* b1      = (const float*)d_in[5];
  const float* W2      = (const float*)d_in[6];
  const float* b2      = (const float*)d_in[7];
  float* out = (float*)d_out;

  hipLaunchKernelGGL(transform_w, dim3(80), dim3(256), 0, stream, W1, W2, (char*)d_ws);
  hipLaunchKernelGGL(fp_mfma, dim3(NB * (N1 / TM)), dim3(512), 0, stream,
                     xyz1, xyz2, points1, points2, (const char*)d_ws, b1, b2, out);
}

// Round 14
// 47.731 us; speedup vs baseline: 1.1311x; 1.1311x over previous
//
#include <hip/hip_runtime.h>

typedef __attribute__((ext_vector_type(8))) short bf16x8;
typedef __attribute__((ext_vector_type(4))) float f32x4;

namespace {
constexpr int NB=8, N1=4096, N2=1024, F1=128, F2=256, H2=256;
constexpr int TM=64;
constexpr float SLOPE=0.2f, EPSD=1e-10f;
constexpr size_t WS_W1=0;                     // 192 KB (12 steps * 16 frags * 1KB)
constexpr size_t WS_W2=196608;                // 128 KB
constexpr int XT_STRIDE=784;   // 48 slots*16B + 16B pad
constexpr int H_STRIDE=528;    // 512B row + 16B pad
}

__device__ __forceinline__ unsigned short f2bf(float f){
  union{float f; unsigned u;} v; v.f=f;
  unsigned r = v.u + 0x7FFFu + ((v.u>>16)&1u);   // RNE
  return (unsigned short)(r>>16);
}
// packed RNE f32x2 -> bf16x2 (bit-identical to f2bf, 1 instr)
__device__ __forceinline__ unsigned cvt_pk_bf16(float lo, float hi){
  unsigned r;
  asm("v_cvt_pk_bf16_f32 %0, %1, %2" : "=v"(r) : "v"(lo), "v"(hi));
  return r;
}
__device__ __forceinline__ float lrelu(float x){ return x>=0.f? x : SLOPE*x; }

// ===== W1/W2 -> bf16 frag-linear: frag = s*16 + nq*4 + nt; lane ln holds 8
// k-bf16 for n = nq*64+nt*16+(ln&15), k0 = s*32+(ln>>4)*8 =====
__global__ __launch_bounds__(256)
void transform_w(const float* __restrict__ W1, const float* __restrict__ W2,
                 char* __restrict__ ws)
{
  int id = blockIdx.x*256 + threadIdx.x;
  const float* src; size_t dst;
  if (id < 12288) {                             // W1: 192 frags
    int frag = id >> 6, ln = id & 63;
    int n = (((frag>>2)&3)*64) + ((frag&3)*16) + (ln & 15);
    int k0 = (frag>>4)*32 + (ln>>4)*8;
    src = W1 + (size_t)k0*256 + n;
    dst = WS_W1 + (size_t)frag*1024 + ln*16;
  } else if (id < 20480) {                      // W2: 128 frags
    int fid = id - 12288, frag = fid >> 6, ln = fid & 63;
    int n = (((frag>>2)&3)*64) + ((frag&3)*16) + (ln & 15);
    int k0 = (frag>>4)*32 + (ln>>4)*8;
    src = W2 + (size_t)k0*256 + n;
    dst = WS_W2 + (size_t)frag*1024 + ln*16;
  } else return;
  unsigned u[4];
  #pragma unroll
  for (int p=0;p<4;++p)
    u[p] = (unsigned)f2bf(src[(2*p)*256]) | ((unsigned)f2bf(src[(2*p+1)*256])<<16);
  *(uint4*)(ws + dst) = make_uint4(u[0],u[1],u[2],u[3]);
}

// TM=64, 512 threads (8 waves = 2m x 4n), grid 512, 2 blocks/CU.
// Scan: R=4 rows/thread (LDS reads /4), 32 slices x 32 j, 2-stage merge.
__global__ __launch_bounds__(512, 4)
void fp_mfma(const float* __restrict__ xyz1, const float* __restrict__ xyz2,
             const float* __restrict__ p1,   const float* __restrict__ p2,
             const char* __restrict__ ws,
             const float* __restrict__ b1,   const float* __restrict__ b2,
             float* __restrict__ out)
{
  extern __shared__ __align__(16) char smem[];   // 65536 dynamic
  __shared__ float s_w[TM][4];
  __shared__ int   s_idx[TM][4];

  const int t = threadIdx.x;
  const int b = blockIdx.x & 7;                // batch == XCD
  const int row0 = (blockIdx.x >> 3) * TM;
  const int lane = t & 63, wv = t >> 6;
  const int lrow = lane & 15, lg = lane >> 4;
  const int mh = wv >> 2, nq = wv & 3;         // wave = (m-half, n-quad)

  // ===== Phase A =====
  {
    float4* xq = (float4*)smem;                // [0, 16384)
    char* cand = smem + 16384;                 // [16384, 65536): 2048 * 24B
    const float* xz = xyz2 + (size_t)b*N2*3;
    for (int j = t; j < N2; j += 512) {
      float x = xz[3*j], y = xz[3*j+1], z = xz[3*j+2];
      xq[j] = make_float4(x, y, z, x*x + y*y + z*z);
    }
    __syncthreads();
    {  // scan: thread = (grp of 4 rows, slice of 32 j); one xq read serves 4 rows
      const int grp = t & 15, slice = t >> 4;
      float px[4], py[4], pz[4], sq1[4];
      float d0[4], d1[4], d2[4]; int i0[4], i1[4], i2[4];
      #pragma unroll
      for (int r=0;r<4;++r){
        const float* x1 = xyz1 + ((size_t)b*N1 + row0 + grp*4 + r)*3;
        px[r]=x1[0]; py[r]=x1[1]; pz[r]=x1[2];
        sq1[r] = px[r]*px[r] + py[r]*py[r] + pz[r]*pz[r];
        d0[r]=d1[r]=d2[r]=3.4e38f; i0[r]=i1[r]=i2[r]=0;
      }
      const int j0 = slice*32;
      #pragma unroll 4
      for (int j=j0; j<j0+32; ++j){
        float4 q = xq[j];
        #pragma unroll
        for (int r=0;r<4;++r){
          float dot = px[r]*q.x + py[r]*q.y + pz[r]*q.z;
          float d = fmaf(-2.f, dot, sq1[r] + q.w);
          bool c0 = d<d0[r], c1 = d<d1[r], c2 = d<d2[r];
          i2[r] = c1 ? i1[r] : (c2 ? j : i2[r]);
          i1[r] = c0 ? i0[r] : (c1 ? j : i1[r]);
          i0[r] = c0 ? j    : i0[r];
          d2[r] = __builtin_amdgcn_fmed3f(d, d1[r], d2[r]);
          d1[r] = __builtin_amdgcn_fmed3f(d, d0[r], d1[r]);
          d0[r] = fminf(d, d0[r]);
        }
      }
      #pragma unroll
      for (int r=0;r<4;++r){
        char* p = cand + ((size_t)(slice*64 + grp*4 + r))*24;
        *(float2*)p = make_float2(d0[r], d1[r]);
        *(float*)(p+8) = d2[r];
        ((int*)p)[3]=i0[r]; ((int*)p)[4]=i1[r]; ((int*)p)[5]=i2[r];
      }
    }
    __syncthreads();
    {  // stage 1: 512 threads, each merges 4 ascending slices -> cand2 [0,12288)
      const int row = t & 63, oct = t >> 6;
      const char* cand_ = smem + 16384;
      float d0=3.4e38f,d1=3.4e38f,d2=3.4e38f; int i0=0,i1=0,i2=0;
      #pragma unroll
      for (int k=0;k<4;++k){
        const char* p = cand_ + ((size_t)((oct*4+k)*64 + row))*24;
        float2 dd = *(const float2*)p;
        float dc0=dd.x, dc1=dd.y, dc2=*(const float*)(p+8);
        int ic0=((const int*)p)[3], ic1=((const int*)p)[4], ic2=((const int*)p)[5];
        float dc[3]={dc0,dc1,dc2}; int ic[3]={ic0,ic1,ic2};
        #pragma unroll
        for (int c=0;c<3;++c){
          float d = dc[c]; int ii = ic[c];
          if (d < d2) {
            if (d < d1) { d2=d1; i2=i1;
              if (d < d0) { d1=d0; i1=i0; d0=d; i0=ii; } else { d1=d; i1=ii; }
            } else { d2=d; i2=ii; }
          }
        }
      }
      char* p2 = smem + (size_t)(oct*64 + row)*24;   // xq dead
      *(float2*)p2 = make_float2(d0, d1);
      *(float*)(p2+8) = d2;
      ((int*)p2)[3]=i0; ((int*)p2)[4]=i1; ((int*)p2)[5]=i2;
    }
    __syncthreads();
    if (t < TM) {                              // stage 2: merge 8 octs, ascending
      float d0=3.4e38f,d1=3.4e38f,d2=3.4e38f; int i0=0,i1=0,i2=0;
      for (int p=0;p<8;++p){
        const char* c2 = smem + (size_t)(p*64 + t)*24;
        float2 dd = *(const float2*)c2;
        float dc[3]={dd.x, dd.y, *(const float*)(c2+8)};
        int ic[3]={((const int*)c2)[3], ((const int*)c2)[4], ((const int*)c2)[5]};
        #pragma unroll
        for (int c=0;c<3;++c){
          float d = dc[c]; int ii = ic[c];
          if (d < d2) {
            if (d < d1) { d2=d1; i2=i1;
              if (d < d0) { d1=d0; i1=i0; d0=d; i0=ii; } else { d1=d; i1=ii; }
            } else { d2=d; i2=ii; }
          }
        }
      }
      d0=fmaxf(d0,EPSD); d1=fmaxf(d1,EPSD); d2=fmaxf(d2,EPSD);
      float w0=1.f/d0, w1=1.f/d1, w2=1.f/d2, inv=1.f/(w0+w1+w2);
      s_w[t][0]=w0*inv; s_w[t][1]=w1*inv; s_w[t][2]=w2*inv;
      s_idx[t][0]=i0; s_idx[t][1]=i1; s_idx[t][2]=i2;
    }
    __syncthreads();
  }

  // ===== Phase B (R12 structure) =====
  const int rr = t >> 3, qq = t & 7;           // X build: 8 thr/row, 6 slots each
  const float w0_=s_w[rr][0], w1_=s_w[rr][1], w2_=s_w[rr][2];
  const int g0=s_idx[rr][0], g1=s_idx[rr][1], g2=s_idx[rr][2];
  const char* wsW1 = ws + WS_W1;
  const char* wsW2 = ws + WS_W2;
  const float* p2b = p2 + (size_t)b*N2*F2;
  const float* p1r = p1 + ((size_t)b*N1 + row0 + rr)*F1;

  auto issueAny = [&](int kcg, float4* g){
    if (kcg < 4) {
      const int k0 = kcg*64 + qq*8;
      const float4* q0 = (const float4*)(p2b + (size_t)g0*F2 + k0);
      const float4* q1 = (const float4*)(p2b + (size_t)g1*F2 + k0);
      const float4* q2 = (const float4*)(p2b + (size_t)g2*F2 + k0);
      g[0]=q0[0]; g[1]=q0[1]; g[2]=q1[0]; g[3]=q1[1]; g[4]=q2[0]; g[5]=q2[1];
    } else {
      const float4* q = (const float4*)(p1r + (kcg*64 + qq*8 - F2));
      g[0]=q[0]; g[1]=q[1];
    }
  };
  auto writeAny = [&](int kcg, const float4* g){
    float v[8];
    if (kcg < 4) {
      #pragma unroll
      for (int p=0;p<2;++p){
        v[4*p+0] = fmaf(w2_, g[4+p].x, fmaf(w1_, g[2+p].x, w0_*g[p].x));
        v[4*p+1] = fmaf(w2_, g[4+p].y, fmaf(w1_, g[2+p].y, w0_*g[p].y));
        v[4*p+2] = fmaf(w2_, g[4+p].z, fmaf(w1_, g[2+p].z, w0_*g[p].z));
        v[4*p+3] = fmaf(w2_, g[4+p].w, fmaf(w1_, g[2+p].w, w0_*g[p].w));
      }
    } else {
      #pragma unroll
      for (int p=0;p<2;++p){
        v[4*p+0]=g[p].x; v[4*p+1]=g[p].y; v[4*p+2]=g[p].z; v[4*p+3]=g[p].w;
      }
    }
    unsigned u[4];
    #pragma unroll
    for (int p=0;p<4;++p) u[p] = cvt_pk_bf16(v[2*p], v[2*p+1]);
    *(uint4*)(smem + rr*XT_STRIDE + (kcg*8 + qq)*16) = make_uint4(u[0],u[1],u[2],u[3]);
  };
  auto loadW = [&](const char* base, int s, bf16x8* dst){
    #pragma unroll
    for (int nt=0;nt<4;++nt)
      dst[nt] = *(const bf16x8*)(base + ((s*16 + nq*4 + nt)<<10) + lane*16);
  };
  auto gemmStep = [&](int s, const bf16x8* bw, f32x4 (&ac)[2][4],
                      const char* Ab, int stride){
    bf16x8 af[2];
    #pragma unroll
    for (int mt=0;mt<2;++mt)
      af[mt] = *(const bf16x8*)(Ab + (mh*32 + mt*16 + lrow)*stride + (s*4+lg)*16);
    #pragma unroll
    for (int mt=0;mt<2;++mt)
      #pragma unroll
      for (int nt=0;nt<4;++nt)
        ac[mt][nt] = __builtin_amdgcn_mfma_f32_16x16x32_bf16(af[mt], bw[nt], ac[mt][nt], 0,0,0);
  };

  f32x4 acc[2][4];
  #pragma unroll
  for (int mt=0;mt<2;++mt)
    #pragma unroll
    for (int nt=0;nt<4;++nt) acc[mt][nt] = (f32x4){0.f,0.f,0.f,0.f};

  // ---- W steps 0..2 prefetch FIRST (L2 latency hides under X build) ----
  bf16x8 bwA[4], bwB[4], bwC[4];
  loadW(wsW1, 0, bwA);
  loadW(wsW1, 1, bwB);
  loadW(wsW1, 2, bwC);

  // ---- build full X tile (64 x 384), depth-2 gather pipeline ----
  float4 ga[6], gb[6];
  issueAny(0, ga); issueAny(1, gb);
  writeAny(0, ga); issueAny(2, ga);
  writeAny(1, gb); issueAny(3, gb);
  writeAny(2, ga); issueAny(4, ga);
  writeAny(3, gb); issueAny(5, gb);
  writeAny(4, ga); writeAny(5, gb);
  __syncthreads();

  // ---- GEMM1: 12 K32 steps, no internal barriers, W prefetch distance 3 ----
  #pragma unroll
  for (int u=0; u<4; ++u) {
    gemmStep(3*u,   bwA, acc, smem, XT_STRIDE);
    if (u<3) loadW(wsW1, 3*u+3, bwA); else loadW(wsW2, 0, bwA);
    gemmStep(3*u+1, bwB, acc, smem, XT_STRIDE);
    if (u<3) loadW(wsW1, 3*u+4, bwB); else loadW(wsW2, 1, bwB);
    gemmStep(3*u+2, bwC, acc, smem, XT_STRIDE);
    if (u<3) loadW(wsW1, 3*u+5, bwC); else loadW(wsW2, 2, bwC);
  }
  __syncthreads();                             // Xt dead

  // ---- h = lrelu(acc + b1) -> LDS [64][264 shorts], cvt_pk pairs ----
  {
    float bb[4];
    #pragma unroll
    for (int nt=0;nt<4;++nt) bb[nt] = b1[nq*64 + nt*16 + lrow];
    #pragma unroll
    for (int mt=0;mt<2;++mt)
      #pragma unroll
      for (int rg=0;rg<4;++rg) {
        const int row = mh*32 + mt*16 + lg*4 + rg;
        char* hb = smem + row*H_STRIDE + (nq*64 + lrow)*2;
        float v0 = lrelu(acc[mt][0][rg] + bb[0]);
        float v1 = lrelu(acc[mt][1][rg] + bb[1]);
        float v2 = lrelu(acc[mt][2][rg] + bb[2]);
        float v3 = lrelu(acc[mt][3][rg] + bb[3]);
        unsigned pA = cvt_pk_bf16(v0, v1), pB = cvt_pk_bf16(v2, v3);
        *(short*)(hb)      = (short)pA;
        *(short*)(hb + 32) = (short)(pA >> 16);
        *(short*)(hb + 64) = (short)pB;
        *(short*)(hb + 96) = (short)(pB >> 16);
      }
  }
  __syncthreads();

  // ---- GEMM2: h(64x256) @ W2, 8 K32 steps, dist-3 rotation ----
  f32x4 acc2[2][4];
  #pragma unroll
  for (int mt=0;mt<2;++mt)
    #pragma unroll
    for (int nt=0;nt<4;++nt) acc2[mt][nt] = (f32x4){0.f,0.f,0.f,0.f};
  gemmStep(0, bwA, acc2, smem, H_STRIDE); loadW(wsW2, 3, bwA);
  gemmStep(1, bwB, acc2, smem, H_STRIDE); loadW(wsW2, 4, bwB);
  gemmStep(2, bwC, acc2, smem, H_STRIDE); loadW(wsW2, 5, bwC);
  gemmStep(3, bwA, acc2, smem, H_STRIDE); loadW(wsW2, 6, bwA);
  gemmStep(4, bwB, acc2, smem, H_STRIDE); loadW(wsW2, 7, bwB);
  gemmStep(5, bwC, acc2, smem, H_STRIDE);
  gemmStep(6, bwA, acc2, smem, H_STRIDE);
  gemmStep(7, bwB, acc2, smem, H_STRIDE);

  // ---- epilogue ----
  {
    float bb[4];
    #pragma unroll
    for (int nt=0;nt<4;++nt) bb[nt] = b2[nq*64 + nt*16 + lrow];
    float* ob = out + ((size_t)b*N1 + row0) * H2;
    #pragma unroll
    for (int mt=0;mt<2;++mt)
      #pragma unroll
      for (int rg=0;rg<4;++rg) {
        const int row = mh*32 + mt*16 + lg*4 + rg;
        #pragma unroll
        for (int nt=0;nt<4;++nt) {
          const int col = nq*64 + nt*16 + lrow;
          ob[(size_t)row*H2 + col] = lrelu(acc2[mt][nt][rg] + bb[nt]);
        }
      }
  }
}

extern "C" void kernel_launch(void* const* d_in, const int* in_sizes, int n_in,
                              void* d_out, int out_size, void* d_ws, size_t ws_size,
                              hipStream_t stream) {
  const float* xyz1    = (const float*)d_in[0];
  const float* xyz2    = (const float*)d_in[1];
  const float* points1 = (const float*)d_in[2];
  const float* points2 = (const float*)d_in[3];
  const float* W1      = (const float*)d_in[4];
  const float* b1      = (const float*)d_in[5];
  const float* W2      = (const float*)d_in[6];
  const float* b2      = (const float*)d_in[7];
  float* out = (float*)d_out;

  hipLaunchKernelGGL(transform_w, dim3(80), dim3(256), 0, stream, W1, W2, (char*)d_ws);
  hipLaunchKernelGGL(fp_mfma, dim3(NB * (N1 / TM)), dim3(512), 65536, stream,
                     xyz1, xyz2, points1, points2, (const char*)d_ws, b1, b2, out);
}

// Round 15
// 46.065 us; speedup vs baseline: 1.1720x; 1.0362x over previous
//
#include <hip/hip_runtime.h>

typedef __attribute__((ext_vector_type(8))) short bf16x8;
typedef __attribute__((ext_vector_type(4))) float f32x4;

namespace {
constexpr int NB=8, N1=4096, N2=1024, F1=128, F2=256, H2=256;
constexpr int TM=64;
constexpr float SLOPE=0.2f, EPSD=1e-10f;
constexpr size_t WS_W1=0;                     // 192 KB (12 steps * 16 frags * 1KB)
constexpr size_t WS_W2=196608;                // 128 KB
constexpr size_t WS_XYZ=327680;               // 8*1024*16 = 128 KB
constexpr int XT_STRIDE=784;   // 48 slots*16B + 16B pad
constexpr int H_STRIDE=528;    // 512B row + 16B pad
}

__device__ __forceinline__ unsigned short f2bf(float f){
  union{float f; unsigned u;} v; v.f=f;
  unsigned r = v.u + 0x7FFFu + ((v.u>>16)&1u);   // RNE
  return (unsigned short)(r>>16);
}
// packed RNE f32x2 -> bf16x2 (bit-identical to f2bf, 1 instr)
__device__ __forceinline__ unsigned cvt_pk_bf16(float lo, float hi){
  unsigned r;
  asm("v_cvt_pk_bf16_f32 %0, %1, %2" : "=v"(r) : "v"(lo), "v"(hi));
  return r;
}
__device__ __forceinline__ float lrelu(float x){ return x>=0.f? x : SLOPE*x; }

// ===== W1/W2 -> bf16 frag-linear; xyz2 -> (x,y,z,|.|^2) table =====
__global__ __launch_bounds__(256)
void transform_w(const float* __restrict__ W1, const float* __restrict__ W2,
                 const float* __restrict__ xyz2, char* __restrict__ ws)
{
  int id = blockIdx.x*256 + threadIdx.x;
  if (id < 12288) {                             // W1: 192 frags
    int frag = id >> 6, ln = id & 63;
    int n = (((frag>>2)&3)*64) + ((frag&3)*16) + (ln & 15);
    int k0 = (frag>>4)*32 + (ln>>4)*8;
    const float* src = W1 + (size_t)k0*256 + n;
    unsigned u[4];
    #pragma unroll
    for (int p=0;p<4;++p)
      u[p] = (unsigned)f2bf(src[(2*p)*256]) | ((unsigned)f2bf(src[(2*p+1)*256])<<16);
    *(uint4*)(ws + WS_W1 + (size_t)frag*1024 + ln*16) = make_uint4(u[0],u[1],u[2],u[3]);
  } else if (id < 20480) {                      // W2: 128 frags
    int fid = id - 12288, frag = fid >> 6, ln = fid & 63;
    int n = (((frag>>2)&3)*64) + ((frag&3)*16) + (ln & 15);
    int k0 = (frag>>4)*32 + (ln>>4)*8;
    const float* src = W2 + (size_t)k0*256 + n;
    unsigned u[4];
    #pragma unroll
    for (int p=0;p<4;++p)
      u[p] = (unsigned)f2bf(src[(2*p)*256]) | ((unsigned)f2bf(src[(2*p+1)*256])<<16);
    *(uint4*)(ws + WS_W2 + (size_t)frag*1024 + ln*16) = make_uint4(u[0],u[1],u[2],u[3]);
  } else if (id < 28672) {                      // xyz2q table
    id -= 20480;
    int bb = id >> 10, j = id & 1023;
    const float* sp = xyz2 + ((size_t)bb*N2 + j)*3;
    float x=sp[0], y=sp[1], z=sp[2];
    *(float4*)(ws + WS_XYZ + ((size_t)bb*1024 + j)*16) =
        make_float4(x,y,z,x*x+y*y+z*z);
  }
}

// TM=64, 512 threads (8 waves = 2m x 4n), grid 512. Scan reads xyz2q via
// SCALAR loads (wave-uniform j, readfirstlane-pinned) -> s_load_dwordx4:
// scan runs on SMEM pipe, LDS/VMEM pipes free.
__global__ __launch_bounds__(512, 2)
void fp_mfma(const float* __restrict__ xyz1, const float* __restrict__ p1,
             const float* __restrict__ p2,   const char* __restrict__ ws,
             const float* __restrict__ b1,   const float* __restrict__ b2,
             float* __restrict__ out)
{
  __shared__ __align__(16) char smem[50176];   // cand 16K -> Xt 50K -> h 34K
  __shared__ float s_w[TM][4];
  __shared__ int   s_idx[TM][4];

  const int t = threadIdx.x;
  const int b = blockIdx.x & 7;                // batch == XCD
  const int row0 = (blockIdx.x >> 3) * TM;
  const int lane = t & 63, wv = t >> 6;
  const int lrow = lane & 15, lg = lane >> 4;
  const int mh = wv >> 2, nq = wv & 3;         // wave = (m-half, n-quad)

  // ===== Phase A: scan via scalar loads; lane = row, wave = j-slice =====
  {
    const float4* xqg = (const float4*)(ws + WS_XYZ + (size_t)b*16384);
    const float* x1 = xyz1 + ((size_t)b*N1 + row0 + lane)*3;
    const float px=x1[0], py=x1[1], pz=x1[2];
    const float sq1 = px*px + py*py + pz*pz;
    float d0=3.4e38f, d1=3.4e38f, d2=3.4e38f;
    int i0=0, i1=0, i2=0;
    const int j0 = __builtin_amdgcn_readfirstlane(wv*128);  // SGPR-pinned
    #pragma unroll 8
    for (int j = j0; j < j0+128; ++j) {
      float4 q = xqg[j];                       // scalar addr -> s_load_dwordx4
      float dot = px*q.x + py*q.y + pz*q.z;
      float d = fmaf(-2.f, dot, sq1 + q.w);
      bool c0 = d < d0, c1 = d < d1, c2 = d < d2;
      i2 = c1 ? i1 : (c2 ? j : i2);
      i1 = c0 ? i0 : (c1 ? j : i1);
      i0 = c0 ? j  : i0;
      d2 = __builtin_amdgcn_fmed3f(d, d1, d2);
      d1 = __builtin_amdgcn_fmed3f(d, d0, d1);
      d0 = fminf(d, d0);
    }
    float* cd = (float*)(smem + (wv*64 + lane)*32);
    cd[0]=d0; cd[1]=d1; cd[2]=d2;
    ((int*)cd)[4]=i0; ((int*)cd)[5]=i1; ((int*)cd)[6]=i2;
  }
  __syncthreads();
  if (t < TM) {                                // merge 8 slices, j-ascending
    float d0=3.4e38f,d1=3.4e38f,d2=3.4e38f; int i0=0,i1=0,i2=0;
    for (int p=0;p<8;++p){
      const float* cd = (const float*)(smem + (p*64 + t)*32);
      for (int c=0;c<3;++c){
        float d = cd[c]; int ii = ((const int*)cd)[4+c];
        if (d < d2) {
          if (d < d1) { d2=d1; i2=i1;
            if (d < d0) { d1=d0; i1=i0; d0=d; i0=ii; } else { d1=d; i1=ii; }
          } else { d2=d; i2=ii; }
        }
      }
    }
    d0=fmaxf(d0,EPSD); d1=fmaxf(d1,EPSD); d2=fmaxf(d2,EPSD);
    float w0=1.f/d0, w1=1.f/d1, w2=1.f/d2, inv=1.f/(w0+w1+w2);
    s_w[t][0]=w0*inv; s_w[t][1]=w1*inv; s_w[t][2]=w2*inv;
    s_idx[t][0]=i0; s_idx[t][1]=i1; s_idx[t][2]=i2;
  }
  __syncthreads();

  // ===== Phase B (R12 structure) =====
  const int rr = t >> 3, qq = t & 7;           // X build: 8 thr/row, 6 slots each
  const float w0_=s_w[rr][0], w1_=s_w[rr][1], w2_=s_w[rr][2];
  const int g0=s_idx[rr][0], g1=s_idx[rr][1], g2=s_idx[rr][2];
  const char* wsW1 = ws + WS_W1;
  const char* wsW2 = ws + WS_W2;
  const float* p2b = p2 + (size_t)b*N2*F2;
  const float* p1r = p1 + ((size_t)b*N1 + row0 + rr)*F1;

  auto issueAny = [&](int kcg, float4* g){
    if (kcg < 4) {
      const int k0 = kcg*64 + qq*8;
      const float4* q0 = (const float4*)(p2b + (size_t)g0*F2 + k0);
      const float4* q1 = (const float4*)(p2b + (size_t)g1*F2 + k0);
      const float4* q2 = (const float4*)(p2b + (size_t)g2*F2 + k0);
      g[0]=q0[0]; g[1]=q0[1]; g[2]=q1[0]; g[3]=q1[1]; g[4]=q2[0]; g[5]=q2[1];
    } else {
      const float4* q = (const float4*)(p1r + (kcg*64 + qq*8 - F2));
      g[0]=q[0]; g[1]=q[1];
    }
  };
  auto writeAny = [&](int kcg, const float4* g){
    float v[8];
    if (kcg < 4) {
      #pragma unroll
      for (int p=0;p<2;++p){
        v[4*p+0] = fmaf(w2_, g[4+p].x, fmaf(w1_, g[2+p].x, w0_*g[p].x));
        v[4*p+1] = fmaf(w2_, g[4+p].y, fmaf(w1_, g[2+p].y, w0_*g[p].y));
        v[4*p+2] = fmaf(w2_, g[4+p].z, fmaf(w1_, g[2+p].z, w0_*g[p].z));
        v[4*p+3] = fmaf(w2_, g[4+p].w, fmaf(w1_, g[2+p].w, w0_*g[p].w));
      }
    } else {
      #pragma unroll
      for (int p=0;p<2;++p){
        v[4*p+0]=g[p].x; v[4*p+1]=g[p].y; v[4*p+2]=g[p].z; v[4*p+3]=g[p].w;
      }
    }
    unsigned u[4];
    #pragma unroll
    for (int p=0;p<4;++p) u[p] = cvt_pk_bf16(v[2*p], v[2*p+1]);
    *(uint4*)(smem + rr*XT_STRIDE + (kcg*8 + qq)*16) = make_uint4(u[0],u[1],u[2],u[3]);
  };
  auto loadW = [&](const char* base, int s, bf16x8* dst){
    #pragma unroll
    for (int nt=0;nt<4;++nt)
      dst[nt] = *(const bf16x8*)(base + ((s*16 + nq*4 + nt)<<10) + lane*16);
  };
  auto gemmStep = [&](int s, const bf16x8* bw, f32x4 (&ac)[2][4],
                      const char* Ab, int stride){
    bf16x8 af[2];
    #pragma unroll
    for (int mt=0;mt<2;++mt)
      af[mt] = *(const bf16x8*)(Ab + (mh*32 + mt*16 + lrow)*stride + (s*4+lg)*16);
    #pragma unroll
    for (int mt=0;mt<2;++mt)
      #pragma unroll
      for (int nt=0;nt<4;++nt)
        ac[mt][nt] = __builtin_amdgcn_mfma_f32_16x16x32_bf16(af[mt], bw[nt], ac[mt][nt], 0,0,0);
  };

  f32x4 acc[2][4];
  #pragma unroll
  for (int mt=0;mt<2;++mt)
    #pragma unroll
    for (int nt=0;nt<4;++nt) acc[mt][nt] = (f32x4){0.f,0.f,0.f,0.f};

  // ---- W steps 0..2 prefetch FIRST (L2 latency hides under X build) ----
  bf16x8 bwA[4], bwB[4], bwC[4];
  loadW(wsW1, 0, bwA);
  loadW(wsW1, 1, bwB);
  loadW(wsW1, 2, bwC);

  // ---- build full X tile (64 x 384), depth-2 gather pipeline ----
  float4 ga[6], gb[6];
  issueAny(0, ga); issueAny(1, gb);
  writeAny(0, ga); issueAny(2, ga);
  writeAny(1, gb); issueAny(3, gb);
  writeAny(2, ga); issueAny(4, ga);
  writeAny(3, gb); issueAny(5, gb);
  writeAny(4, ga); writeAny(5, gb);
  __syncthreads();

  // ---- GEMM1: 12 K32 steps, no internal barriers, W prefetch distance 3 ----
  #pragma unroll
  for (int u=0; u<4; ++u) {
    gemmStep(3*u,   bwA, acc, smem, XT_STRIDE);
    if (u<3) loadW(wsW1, 3*u+3, bwA); else loadW(wsW2, 0, bwA);
    gemmStep(3*u+1, bwB, acc, smem, XT_STRIDE);
    if (u<3) loadW(wsW1, 3*u+4, bwB); else loadW(wsW2, 1, bwB);
    gemmStep(3*u+2, bwC, acc, smem, XT_STRIDE);
    if (u<3) loadW(wsW1, 3*u+5, bwC); else loadW(wsW2, 2, bwC);
  }
  __syncthreads();                             // Xt dead

  // ---- h = lrelu(acc + b1) -> LDS [64][264 shorts], cvt_pk pairs ----
  {
    float bb[4];
    #pragma unroll
    for (int nt=0;nt<4;++nt) bb[nt] = b1[nq*64 + nt*16 + lrow];
    #pragma unroll
    for (int mt=0;mt<2;++mt)
      #pragma unroll
      for (int rg=0;rg<4;++rg) {
        const int row = mh*32 + mt*16 + lg*4 + rg;
        char* hb = smem + row*H_STRIDE + (nq*64 + lrow)*2;
        float v0 = lrelu(acc[mt][0][rg] + bb[0]);
        float v1 = lrelu(acc[mt][1][rg] + bb[1]);
        float v2 = lrelu(acc[mt][2][rg] + bb[2]);
        float v3 = lrelu(acc[mt][3][rg] + bb[3]);
        unsigned pA = cvt_pk_bf16(v0, v1), pB = cvt_pk_bf16(v2, v3);
        *(short*)(hb)      = (short)pA;
        *(short*)(hb + 32) = (short)(pA >> 16);
        *(short*)(hb + 64) = (short)pB;
        *(short*)(hb + 96) = (short)(pB >> 16);
      }
  }
  __syncthreads();

  // ---- GEMM2: h(64x256) @ W2, 8 K32 steps, dist-3 rotation ----
  f32x4 acc2[2][4];
  #pragma unroll
  for (int mt=0;mt<2;++mt)
    #pragma unroll
    for (int nt=0;nt<4;++nt) acc2[mt][nt] = (f32x4){0.f,0.f,0.f,0.f};
  gemmStep(0, bwA, acc2, smem, H_STRIDE); loadW(wsW2, 3, bwA);
  gemmStep(1, bwB, acc2, smem, H_STRIDE); loadW(wsW2, 4, bwB);
  gemmStep(2, bwC, acc2, smem, H_STRIDE); loadW(wsW2, 5, bwC);
  gemmStep(3, bwA, acc2, smem, H_STRIDE); loadW(wsW2, 6, bwA);
  gemmStep(4, bwB, acc2, smem, H_STRIDE); loadW(wsW2, 7, bwB);
  gemmStep(5, bwC, acc2, smem, H_STRIDE);
  gemmStep(6, bwA, acc2, smem, H_STRIDE);
  gemmStep(7, bwB, acc2, smem, H_STRIDE);

  // ---- epilogue ----
  {
    float bb[4];
    #pragma unroll
    for (int nt=0;nt<4;++nt) bb[nt] = b2[nq*64 + nt*16 + lrow];
    float* ob = out + ((size_t)b*N1 + row0) * H2;
    #pragma unroll
    for (int mt=0;mt<2;++mt)
      #pragma unroll
      for (int rg=0;rg<4;++rg) {
        const int row = mh*32 + mt*16 + lg*4 + rg;
        #pragma unroll
        for (int nt=0;nt<4;++nt) {
          const int col = nq*64 + nt*16 + lrow;
          ob[(size_t)row*H2 + col] = lrelu(acc2[mt][nt][rg] + bb[nt]);
        }
      }
  }
}

extern "C" void kernel_launch(void* const* d_in, const int* in_sizes, int n_in,
                              void* d_out, int out_size, void* d_ws, size_t ws_size,
                              hipStream_t stream) {
  const float* xyz1    = (const float*)d_in[0];
  const float* xyz2    = (const float*)d_in[1];
  const float* points1 = (const float*)d_in[2];
  const float* points2 = (const float*)d_in[3];
  const float* W1      = (const float*)d_in[4];
  const float* b1      = (const float*)d_in[5];
  const float* W2      = (const float*)d_in[6];
  const float* b2      = (const float*)d_in[7];
  float* out = (float*)d_out;

  hipLaunchKernelGGL(transform_w, dim3(112), dim3(256), 0, stream,
                     W1, W2, xyz2, (char*)d_ws);
  hipLaunchKernelGGL(fp_mfma, dim3(NB * (N1 / TM)), dim3(512), 0, stream,
                     xyz1, points1, points2, (const char*)d_ws, b1, b2, out);
}

// Round 16
// 43.657 us; speedup vs baseline: 1.2367x; 1.0552x over previous
//
#include <hip/hip_runtime.h>

typedef __attribute__((ext_vector_type(8))) short bf16x8;
typedef __attribute__((ext_vector_type(4))) float f32x4;

namespace {
constexpr int NB=8, N1=4096, N2=1024, F1=128, F2=256, H2=256;
constexpr int TM=32;
constexpr float SLOPE=0.2f, EPSD=1e-10f;
constexpr size_t WS_W1=0;                     // 192 KB (12 steps * 16 frags * 1KB)
constexpr size_t WS_W2=196608;                // 128 KB
constexpr int XT_STRIDE=784;   // 48 slots*16B + 16B pad
constexpr int H_STRIDE=528;    // 512B row + 16B pad
}

__device__ __forceinline__ unsigned short f2bf(float f){
  union{float f; unsigned u;} v; v.f=f;
  unsigned r = v.u + 0x7FFFu + ((v.u>>16)&1u);   // RNE
  return (unsigned short)(r>>16);
}
// packed RNE f32x2 -> bf16x2 (bit-identical to f2bf; verified R12/R14/R15)
__device__ __forceinline__ unsigned cvt_pk_bf16(float lo, float hi){
  unsigned r;
  asm("v_cvt_pk_bf16_f32 %0, %1, %2" : "=v"(r) : "v"(lo), "v"(hi));
  return r;
}
__device__ __forceinline__ float lrelu(float x){ return x>=0.f? x : SLOPE*x; }

// ===== W1/W2 -> bf16 frag-linear: frag = s*16 + nq*4 + nt; lane ln holds 8
// k-bf16 for n = nq*64+nt*16+(ln&15), k0 = s*32+(ln>>4)*8 =====
__global__ __launch_bounds__(256)
void transform_w(const float* __restrict__ W1, const float* __restrict__ W2,
                 char* __restrict__ ws)
{
  int id = blockIdx.x*256 + threadIdx.x;
  const float* src; size_t dst;
  if (id < 12288) {                             // W1: 192 frags
    int frag = id >> 6, ln = id & 63;
    int n = (((frag>>2)&3)*64) + ((frag&3)*16) + (ln & 15);
    int k0 = (frag>>4)*32 + (ln>>4)*8;
    src = W1 + (size_t)k0*256 + n;
    dst = WS_W1 + (size_t)frag*1024 + ln*16;
  } else if (id < 20480) {                      // W2: 128 frags
    int fid = id - 12288, frag = fid >> 6, ln = fid & 63;
    int n = (((frag>>2)&3)*64) + ((frag&3)*16) + (ln & 15);
    int k0 = (frag>>4)*32 + (ln>>4)*8;
    src = W2 + (size_t)k0*256 + n;
    dst = WS_W2 + (size_t)frag*1024 + ln*16;
  } else return;
  unsigned u[4];
  #pragma unroll
  for (int p=0;p<4;++p)
    u[p] = (unsigned)f2bf(src[(2*p)*256]) | ((unsigned)f2bf(src[(2*p+1)*256])<<16);
  *(uint4*)(ws + dst) = make_uint4(u[0],u[1],u[2],u[3]);
}

// R10 config (measured best 44.3): TM=32, 256 threads, grid 1024, no VGPR cap.
__global__ __launch_bounds__(256, 2)
void fp_mfma(const float* __restrict__ xyz1, const float* __restrict__ xyz2,
             const float* __restrict__ p1,   const float* __restrict__ p2,
             const char* __restrict__ ws,
             const float* __restrict__ b1,   const float* __restrict__ b2,
             float* __restrict__ out)
{
  __shared__ __align__(16) char smem[25088];   // xq 16K + cand 8K; reused: Xt/h
  __shared__ float s_w[TM][4];
  __shared__ int   s_idx[TM][4];

  const int t = threadIdx.x;
  const int b = blockIdx.x & 7;                // batch == XCD
  const int row0 = (blockIdx.x >> 3) * TM;
  const int lane = t & 63, wv = t >> 6;
  const int lrow = lane & 15, lg = lane >> 4;
  const int nq = wv;

  // ===== Phase A: stage xyz2 -> LDS (x,y,z,sq), then 3-NN scan from LDS =====
  {
    float4* xq = (float4*)smem;                // [0, 16384)
    char* cand = smem + 16384;                 // [16384, 24576)
    const float* xz = xyz2 + (size_t)b*N2*3;
    for (int j = t; j < N2; j += 256) {
      float x = xz[3*j], y = xz[3*j+1], z = xz[3*j+2];
      xq[j] = make_float4(x, y, z, x*x + y*y + z*z);
    }
    __syncthreads();
    {
      const int row = lane & 31, slice = wv*2 + (lane >> 5);  // LDS broadcast reads
      const float* x1 = xyz1 + ((size_t)b*N1 + row0 + row)*3;
      const float px=x1[0], py=x1[1], pz=x1[2];
      const float sq1 = px*px + py*py + pz*pz;
      float d0=3.4e38f, d1=3.4e38f, d2=3.4e38f;
      int i0=0, i1=0, i2=0;
      const int j0 = slice*128;
      #pragma unroll 8
      for (int j = j0; j < j0+128; ++j) {
        float4 q = xq[j];
        float dot = px*q.x + py*q.y + pz*q.z;
        float d = fmaf(-2.f, dot, sq1 + q.w);
        bool c0 = d < d0, c1 = d < d1, c2 = d < d2;
        i2 = c1 ? i1 : (c2 ? j : i2);
        i1 = c0 ? i0 : (c1 ? j : i1);
        i0 = c0 ? j  : i0;
        d2 = __builtin_amdgcn_fmed3f(d, d1, d2);
        d1 = __builtin_amdgcn_fmed3f(d, d0, d1);
        d0 = fminf(d, d0);
      }
      float* cd = (float*)(cand + (slice*32 + row)*32);
      cd[0]=d0; cd[1]=d1; cd[2]=d2;
      ((int*)cd)[4]=i0; ((int*)cd)[5]=i1; ((int*)cd)[6]=i2;
    }
    __syncthreads();
    if (t < TM) {                              // merge 8 slices, j-ascending
      const char* cand_ = smem + 16384;
      float d0=3.4e38f,d1=3.4e38f,d2=3.4e38f; int i0=0,i1=0,i2=0;
      for (int p=0;p<8;++p){
        const float* cd = (const float*)(cand_ + (p*32 + t)*32);
        for (int c=0;c<3;++c){
          float d = cd[c]; int ii = ((const int*)cd)[4+c];
          if (d < d2) {
            if (d < d1) { d2=d1; i2=i1;
              if (d < d0) { d1=d0; i1=i0; d0=d; i0=ii; } else { d1=d; i1=ii; }
            } else { d2=d; i2=ii; }
          }
        }
      }
      d0=fmaxf(d0,EPSD); d1=fmaxf(d1,EPSD); d2=fmaxf(d2,EPSD);
      float w0=1.f/d0, w1=1.f/d1, w2=1.f/d2, inv=1.f/(w0+w1+w2);
      s_w[t][0]=w0*inv; s_w[t][1]=w1*inv; s_w[t][2]=w2*inv;
      s_idx[t][0]=i0; s_idx[t][1]=i1; s_idx[t][2]=i2;
    }
    __syncthreads();
  }

  // ===== Phase B =====
  const int rr = t >> 3, qq = t & 7;           // X build: 8 thr/row, 6 chunks
  const float w0_=s_w[rr][0], w1_=s_w[rr][1], w2_=s_w[rr][2];
  const int g0=s_idx[rr][0], g1=s_idx[rr][1], g2=s_idx[rr][2];
  const char* wsW1 = ws + WS_W1;
  const char* wsW2 = ws + WS_W2;
  const float* p2b = p2 + (size_t)b*N2*F2;
  const float* p1r = p1 + ((size_t)b*N1 + row0 + rr)*F1;

  auto issueAny = [&](int kcg, float4* g){
    if (kcg < 4) {
      const int k0 = kcg*64 + qq*8;
      const float4* q0 = (const float4*)(p2b + (size_t)g0*F2 + k0);
      const float4* q1 = (const float4*)(p2b + (size_t)g1*F2 + k0);
      const float4* q2 = (const float4*)(p2b + (size_t)g2*F2 + k0);
      g[0]=q0[0]; g[1]=q0[1]; g[2]=q1[0]; g[3]=q1[1]; g[4]=q2[0]; g[5]=q2[1];
    } else {
      const float4* q = (const float4*)(p1r + (kcg*64 + qq*8 - F2));
      g[0]=q[0]; g[1]=q[1];
    }
  };
  auto writeAny = [&](int kcg, const float4* g){
    float v[8];
    if (kcg < 4) {
      #pragma unroll
      for (int p=0;p<2;++p){
        v[4*p+0] = fmaf(w2_, g[4+p].x, fmaf(w1_, g[2+p].x, w0_*g[p].x));
        v[4*p+1] = fmaf(w2_, g[4+p].y, fmaf(w1_, g[2+p].y, w0_*g[p].y));
        v[4*p+2] = fmaf(w2_, g[4+p].z, fmaf(w1_, g[2+p].z, w0_*g[p].z));
        v[4*p+3] = fmaf(w2_, g[4+p].w, fmaf(w1_, g[2+p].w, w0_*g[p].w));
      }
    } else {
      #pragma unroll
      for (int p=0;p<2;++p){
        v[4*p+0]=g[p].x; v[4*p+1]=g[p].y; v[4*p+2]=g[p].z; v[4*p+3]=g[p].w;
      }
    }
    unsigned u[4];
    #pragma unroll
    for (int p=0;p<4;++p) u[p] = cvt_pk_bf16(v[2*p], v[2*p+1]);
    *(uint4*)(smem + rr*XT_STRIDE + (kcg*8 + qq)*16) = make_uint4(u[0],u[1],u[2],u[3]);
  };
  auto loadW = [&](const char* base, int s, bf16x8* dst){
    #pragma unroll
    for (int nt=0;nt<4;++nt)
      dst[nt] = *(const bf16x8*)(base + ((s*16 + nq*4 + nt)<<10) + lane*16);
  };
  auto gemmStep = [&](int s, const bf16x8* bw, f32x4 (&ac)[2][4],
                      const char* Ab, int stride){
    bf16x8 af[2];
    #pragma unroll
    for (int mt=0;mt<2;++mt)
      af[mt] = *(const bf16x8*)(Ab + (mt*16+lrow)*stride + (s*4+lg)*16);
    #pragma unroll
    for (int mt=0;mt<2;++mt)
      #pragma unroll
      for (int nt=0;nt<4;++nt)
        ac[mt][nt] = __builtin_amdgcn_mfma_f32_16x16x32_bf16(af[mt], bw[nt], ac[mt][nt], 0,0,0);
  };

  f32x4 acc[2][4];
  #pragma unroll
  for (int mt=0;mt<2;++mt)
    #pragma unroll
    for (int nt=0;nt<4;++nt) acc[mt][nt] = (f32x4){0.f,0.f,0.f,0.f};

  // ---- W steps 0..2 prefetch FIRST (L2 latency hides under X build) ----
  bf16x8 bwA[4], bwB[4], bwC[4];
  loadW(wsW1, 0, bwA);
  loadW(wsW1, 1, bwB);
  loadW(wsW1, 2, bwC);

  // ---- build full X tile (32 x 384), depth-2 gather pipeline ----
  float4 ga[6], gb[6];
  issueAny(0, ga); issueAny(1, gb);
  writeAny(0, ga); issueAny(2, ga);
  writeAny(1, gb); issueAny(3, gb);
  writeAny(2, ga); issueAny(4, ga);
  writeAny(3, gb); issueAny(5, gb);
  writeAny(4, ga); writeAny(5, gb);
  __syncthreads();

  // ---- GEMM1: 12 K32 steps, no internal barriers, W prefetch distance 3 ----
  #pragma unroll
  for (int u=0; u<4; ++u) {
    gemmStep(3*u,   bwA, acc, smem, XT_STRIDE);
    if (u<3) loadW(wsW1, 3*u+3, bwA); else loadW(wsW2, 0, bwA);
    gemmStep(3*u+1, bwB, acc, smem, XT_STRIDE);
    if (u<3) loadW(wsW1, 3*u+4, bwB); else loadW(wsW2, 1, bwB);
    gemmStep(3*u+2, bwC, acc, smem, XT_STRIDE);
    if (u<3) loadW(wsW1, 3*u+5, bwC); else loadW(wsW2, 2, bwC);
  }
  __syncthreads();                             // Xt dead

  // ---- h = lrelu(acc + b1) -> LDS [32][264 shorts], cvt_pk pairs ----
  {
    float bb[4];
    #pragma unroll
    for (int nt=0;nt<4;++nt) bb[nt] = b1[nq*64 + nt*16 + lrow];
    #pragma unroll
    for (int mt=0;mt<2;++mt)
      #pragma unroll
      for (int rg=0;rg<4;++rg) {
        const int row = mt*16 + lg*4 + rg;
        char* hb = smem + row*H_STRIDE + (nq*64 + lrow)*2;
        float v0 = lrelu(acc[mt][0][rg] + bb[0]);
        float v1 = lrelu(acc[mt][1][rg] + bb[1]);
        float v2 = lrelu(acc[mt][2][rg] + bb[2]);
        float v3 = lrelu(acc[mt][3][rg] + bb[3]);
        unsigned pA = cvt_pk_bf16(v0, v1), pB = cvt_pk_bf16(v2, v3);
        *(short*)(hb)      = (short)pA;
        *(short*)(hb + 32) = (short)(pA >> 16);
        *(short*)(hb + 64) = (short)pB;
        *(short*)(hb + 96) = (short)(pB >> 16);
      }
  }
  __syncthreads();

  // ---- GEMM2: h(32x256) @ W2, 8 K32 steps, dist-3 rotation ----
  f32x4 acc2[2][4];
  #pragma unroll
  for (int mt=0;mt<2;++mt)
    #pragma unroll
    for (int nt=0;nt<4;++nt) acc2[mt][nt] = (f32x4){0.f,0.f,0.f,0.f};
  gemmStep(0, bwA, acc2, smem, H_STRIDE); loadW(wsW2, 3, bwA);
  gemmStep(1, bwB, acc2, smem, H_STRIDE); loadW(wsW2, 4, bwB);
  gemmStep(2, bwC, acc2, smem, H_STRIDE); loadW(wsW2, 5, bwC);
  gemmStep(3, bwA, acc2, smem, H_STRIDE); loadW(wsW2, 6, bwA);
  gemmStep(4, bwB, acc2, smem, H_STRIDE); loadW(wsW2, 7, bwB);
  gemmStep(5, bwC, acc2, smem, H_STRIDE);
  gemmStep(6, bwA, acc2, smem, H_STRIDE);
  gemmStep(7, bwB, acc2, smem, H_STRIDE);

  // ---- epilogue ----
  {
    float bb[4];
    #pragma unroll
    for (int nt=0;nt<4;++nt) bb[nt] = b2[nq*64 + nt*16 + lrow];
    float* ob = out + ((size_t)b*N1 + row0) * H2;
    #pragma unroll
    for (int mt=0;mt<2;++mt)
      #pragma unroll
      for (int rg=0;rg<4;++rg) {
        const int row = mt*16 + lg*4 + rg;
        #pragma unroll
        for (int nt=0;nt<4;++nt) {
          const int col = nq*64 + nt*16 + lrow;
          ob[(size_t)row*H2 + col] = lrelu(acc2[mt][nt][rg] + bb[nt]);
        }
      }
  }
}

extern "C" void kernel_launch(void* const* d_in, const int* in_sizes, int n_in,
                              void* d_out, int out_size, void* d_ws, size_t ws_size,
                              hipStream_t stream) {
  const float* xyz1    = (const float*)d_in[0];
  const float* xyz2    = (const float*)d_in[1];
  const float* points1 = (const float*)d_in[2];
  const float* points2 = (const float*)d_in[3];
  const float* W1      = (const float*)d_in[4];
  const float* b1      = (const float*)d_in[5];
  const float* W2      = (const float*)d_in[6];
  const float* b2      = (const float*)d_in[7];
  float* out = (float*)d_out;

  hipLaunchKernelGGL(transform_w, dim3(80), dim3(256), 0, stream, W1, W2, (char*)d_ws);
  hipLaunchKernelGGL(fp_mfma, dim3(NB * (N1 / TM)), dim3(256), 0, stream,
                     xyz1, xyz2, points1, points2, (const char*)d_ws, b1, b2, out);
}